// Round 1
// 137.566 us; speedup vs baseline: 1.0027x; 1.0027x over previous
//
#include <hip/hip_runtime.h>
#include <hip/hip_bf16.h>

// ODEFunc CNF dynamics, B=1e6 rows, H=64:
//   h1 = elu(W1 z + b1); [h2|u2|v2] = [h1|u|v] W2^T; out01 = W3 elu(h2)+b3;
//   trace = W3[0,:]*(elu'(h2)*u2) + W3[1,:]*(elu'(h2)*v2); out[:,2] = -trace
//
// R6 (prev): MFMA rewrite, 16-row tiles/wave, no LDS, waves_per_eu(2,2): 74us/dispatch.
//   Counters: MfmaUtil 13, VALUBusy 56, Occupancy 18.8 -> latency-bound at 2 waves/SIMD.
//   Root cause: 128 regs of loop-invariant constants (w0v/w1v/b1v 48 + b2v/w30v/w31v 48
//   + aW2 32) + 48 acc + frags => ~176 unified regs => occupancy pinned.
// R7 (this): free the register file.
//   - per-lane constants -> LDS (1.5KB), re-read per tile via ds_read_b128
//     (quad-broadcast addresses, conflict-free; LDS pipe overlaps VALU/MFMA).
//     Opaque cofs (asm "+v") defeats LICM so they stay out of registers.
//   - z loads: 1 coalesced dword/lane (lanes 0-47 cover the tile's 48 floats)
//     + 2 shfl, software-prefetched one grid-stride iteration ahead.
//   - waves_per_eu(3,3): cap 168 unified regs -> 3 waves/SIMD; grid 1536 = 2
//     balanced rounds of the 768 resident blocks.

typedef short bf16x8 __attribute__((ext_vector_type(8)));
typedef float f32x4  __attribute__((ext_vector_type(4)));

static __device__ __forceinline__ short f2bf(float x) {
    __hip_bfloat16 b = __float2bfloat16(x);
    return __builtin_bit_cast(short, b);
}

__global__ __launch_bounds__(256) __attribute__((amdgpu_waves_per_eu(3, 3)))
void odefunc_mfma(const float* __restrict__ zin,
                  const float* __restrict__ W1, const float* __restrict__ b1,
                  const float* __restrict__ W2, const float* __restrict__ b2,
                  const float* __restrict__ W3, const float* __restrict__ b3,
                  float* __restrict__ out, int B, int ntiles)
{
    // LDS constant bank, f32x4 units: [0..15]=W1 col0, [16..31]=W1 col1,
    // [32..47]=b1, [48..63]=b2, [64..79]=W3 row0, [80..95]=W3 row1
    __shared__ f32x4 sC[96];

    const int lane = threadIdx.x & 63;
    const int quad = lane >> 4;      // 0..3
    const int col  = lane & 15;      // row-within-tile

    if (threadIdx.x < 64) {
        int i = threadIdx.x;
        float* s = (float*)sC;
        s[i]       = W1[2*i];
        s[64 + i]  = W1[2*i + 1];
        s[128 + i] = b1[i];
        s[192 + i] = b2[i];
        s[256 + i] = W3[i];         // W3[0,:]
        s[320 + i] = W3[64 + i];    // W3[1,:]
    }

    const int wid    = blockIdx.x * (blockDim.x >> 6) + (threadIdx.x >> 6);
    const int nwaves = gridDim.x * (blockDim.x >> 6);

    // ---- Loop-invariant: W2 as A-operand fragments (stays in VGPRs: MFMA operand) ----
    bf16x8 aW2[4][2];
#pragma unroll
    for (int mt = 0; mt < 4; ++mt)
#pragma unroll
        for (int jt = 0; jt < 2; ++jt) {
            const float* p = W2 + (mt * 16 + col) * 64 + jt * 32 + quad * 8;
#pragma unroll
            for (int jj = 0; jj < 8; ++jj) aW2[mt][jt][jj] = f2bf(p[jj]);
        }

    const float b30 = b3[0], b31 = b3[1];
    const f32x4 zero4 = {0.f, 0.f, 0.f, 0.f};

    __syncthreads();

    // ---- coalesced z: lanes 0-47 cover the tile's 16 rows x 3 floats ----
    const int lload = lane < 48 ? lane : 47;
    int t = wid;
    float zv = 0.f;
    if (t < ntiles) zv = zin[t * 48 + lload];

    int cofs = 0;   // opaque zero: defeats LICM on the sC re-reads
    for (; t < ntiles; t += nwaves) {
        asm volatile("" : "+v"(cofs));

        // prefetch next tile's z (hides HBM latency under this tile's compute)
        int tn = t + nwaves;
        int tc = tn < ntiles ? tn : t;
        float zvn = zin[tc * 48 + lload];

        float z0 = __shfl(zv, 3 * col);
        float z1 = __shfl(zv, 3 * col + 1);

        // ---- layer 1 (branch-free elu) + B-fragments for [h|u|v] ----
        bf16x8 Ah[2], Au[2], Av[2];
#pragma unroll
        for (int jt = 0; jt < 2; ++jt) {
            int j4 = cofs + jt * 8 + quad * 2;          // f32x4 index of j0 = jt*32+quad*8
            f32x4 w0a = sC[j4],      w0b = sC[j4 + 1];
            f32x4 w1a = sC[j4 + 16], w1b = sC[j4 + 17];
            f32x4 bba = sC[j4 + 32], bbb = sC[j4 + 33];
#pragma unroll
            for (int jj = 0; jj < 8; ++jj) {
                float w0 = (jj < 4) ? w0a[jj & 3] : w0b[jj & 3];
                float w1 = (jj < 4) ? w1a[jj & 3] : w1b[jj & 3];
                float bb = (jj < 4) ? bba[jj & 3] : bbb[jj & 3];
                float a  = fmaf(w0, z0, fmaf(w1, z1, bb));
                float ex = __expf(fminf(a, 0.f));       // elu'(a)
                float h  = fmaxf(a, 0.f) + (ex - 1.f);  // elu(a)
                Ah[jt][jj] = f2bf(h);
                Au[jt][jj] = f2bf(ex * w0);
                Av[jt][jj] = f2bf(ex * w1);
            }
        }

        // ---- MFMA: D = W2 * [h|u|v]^T, K=64 as 2 chained k-steps ----
        f32x4 accH[4], accU[4], accV[4];
#pragma unroll
        for (int mt = 0; mt < 4; ++mt) {
            accH[mt] = __builtin_amdgcn_mfma_f32_16x16x32_bf16(aW2[mt][0], Ah[0], zero4, 0, 0, 0);
            accH[mt] = __builtin_amdgcn_mfma_f32_16x16x32_bf16(aW2[mt][1], Ah[1], accH[mt], 0, 0, 0);
            accU[mt] = __builtin_amdgcn_mfma_f32_16x16x32_bf16(aW2[mt][0], Au[0], zero4, 0, 0, 0);
            accU[mt] = __builtin_amdgcn_mfma_f32_16x16x32_bf16(aW2[mt][1], Au[1], accU[mt], 0, 0, 0);
            accV[mt] = __builtin_amdgcn_mfma_f32_16x16x32_bf16(aW2[mt][0], Av[0], zero4, 0, 0, 0);
            accV[mt] = __builtin_amdgcn_mfma_f32_16x16x32_bf16(aW2[mt][1], Av[1], accV[mt], 0, 0, 0);
        }

        // ---- epilogue: elu + W3 fold, in-lane over this lane's 16 k's ----
        float o0 = 0.f, o1 = 0.f, trc = 0.f;
#pragma unroll
        for (int mt = 0; mt < 4; ++mt) {
            int k4 = cofs + 48 + mt * 4 + quad;         // f32x4 index of k0 = mt*16+quad*4
            f32x4 b2v = sC[k4];
            f32x4 w30 = sC[k4 + 16];
            f32x4 w31 = sC[k4 + 32];
#pragma unroll
            for (int i = 0; i < 4; ++i) {
                float a2  = accH[mt][i] + b2v[i];
                float ex2 = __expf(fminf(a2, 0.f));
                float hh  = fmaxf(a2, 0.f) + (ex2 - 1.f);
                o0  = fmaf(w30[i], hh, o0);
                o1  = fmaf(w31[i], hh, o1);
                trc = fmaf(ex2, fmaf(w30[i], accU[mt][i], w31[i] * accV[mt][i]), trc);
            }
        }

        // ---- cross-quad reduction (k spans quads): 2 butterfly stages ----
        o0  += __shfl_xor(o0, 16);  o0  += __shfl_xor(o0, 32);
        o1  += __shfl_xor(o1, 16);  o1  += __shfl_xor(o1, 32);
        trc += __shfl_xor(trc, 16); trc += __shfl_xor(trc, 32);

        int row = t * 16 + col;
        if (lane < 16 && row < B) {
            out[3 * row + 0] = o0 + b30;
            out[3 * row + 1] = o1 + b31;
            out[3 * row + 2] = -trc;
        }

        zv = zvn;
    }
}

extern "C" void kernel_launch(void* const* d_in, const int* in_sizes, int n_in,
                              void* d_out, int out_size, void* d_ws, size_t ws_size,
                              hipStream_t stream) {
    // d_in: 0=t(unused) 1=z_and_logp 2=W1 3=b1 4=W2 5=b2 6=W3 7=b3
    const float* zin = (const float*)d_in[1];
    const float* W1  = (const float*)d_in[2];
    const float* b1  = (const float*)d_in[3];
    const float* W2  = (const float*)d_in[4];
    const float* b2  = (const float*)d_in[5];
    const float* W3  = (const float*)d_in[6];
    const float* b3  = (const float*)d_in[7];
    float* out = (float*)d_out;

    int B = in_sizes[1] / 3;
    int ntiles = (B + 15) / 16;
    int grid = 1536;   // 3 waves/SIMD -> 768 resident blocks -> 2 balanced rounds
    odefunc_mfma<<<grid, 256, 0, stream>>>(zin, W1, b1, W2, b2, W3, b3,
                                           out, B, ntiles);
}

// Round 2
// 128.890 us; speedup vs baseline: 1.0702x; 1.0673x over previous
//
#include <hip/hip_runtime.h>
#include <hip/hip_bf16.h>

// ODEFunc CNF dynamics, B=1e6 rows, H=64:
//   h1 = elu(W1 z + b1); h2 = W2 h1 + b2; out01 = W3 elu(h2)+b3;
//   trace = sum_k elu'(h2_k) * [W3[0,k] u2_k + W3[1,k] v2_k]; out[:,2] = -trace
//
// R6: MFMA rewrite (16-row tiles/wave, D = W2*[h|u|v]^T): 74us/dispatch.
// R7: consts->LDS, z prefetch, 3 waves/SIMD: occupancy 18.8->25.9, VALUBusy
//     56->63.5, dur UNCHANGED 74us. => VALU-inst-throughput bound (~930
//     wave-insts/tile vs ~120 cyc MFMA). Occupancy is not the lever.
// R8 (this): algebraic VALU cut.
//   (a) Trace fold: trace = sum_k ex2_k * sum_j G[k,j] ex1_j with
//       G[k,j] = W2[k,j]*(W3[0,k]*W1[j,0] + W3[1,k]*W1[j,1])  (loop-invariant,
//       precomputed bf16 A-fragments). Kills u/v muls, one B-fragment set,
//       8 of 24 MFMAs, 16 acc regs.
//   (b) v_cvt_pk_bf16_f32 (HW packed bf16 cvt, T12-verified on gfx950) builds
//       the B-fragment dwords directly: 16 cvt_pk/tile replaces ~48 software
//       RNE conversions + repacking.
// Layouts (m120-verified, carried from R6):
//   A-frag  A[m=col][k=jt*32+quad*8+jj], B-frag B[k][n=col],
//   D[m=mt*16+quad*4+i][n=col].

typedef short bf16x8 __attribute__((ext_vector_type(8)));
typedef float f32x4  __attribute__((ext_vector_type(4)));
typedef int   i32x4  __attribute__((ext_vector_type(4)));

static __device__ __forceinline__ short f2bf(float x) {
    __hip_bfloat16 b = __float2bfloat16(x);
    return __builtin_bit_cast(short, b);
}

// one dword = bf16(lo) | bf16(hi)<<16, single HW instruction
static __device__ __forceinline__ int cvt_pk_bf16(float lo, float hi) {
    int r;
    asm("v_cvt_pk_bf16_f32 %0, %1, %2" : "=v"(r) : "v"(lo), "v"(hi));
    return r;
}

__global__ __launch_bounds__(256) __attribute__((amdgpu_waves_per_eu(3, 3)))
void odefunc_mfma(const float* __restrict__ zin,
                  const float* __restrict__ W1, const float* __restrict__ b1,
                  const float* __restrict__ W2, const float* __restrict__ b2,
                  const float* __restrict__ W3, const float* __restrict__ b3,
                  float* __restrict__ out, int B, int ntiles)
{
    // LDS constant bank, f32x4 units: [0..15]=W1 col0, [16..31]=W1 col1,
    // [32..47]=b1, [48..63]=b2, [64..79]=W3 row0, [80..95]=W3 row1
    __shared__ f32x4 sC[96];

    const int lane = threadIdx.x & 63;
    const int quad = lane >> 4;      // 0..3
    const int col  = lane & 15;      // row-within-tile

    if (threadIdx.x < 64) {
        int i = threadIdx.x;
        float* s = (float*)sC;
        s[i]       = W1[2*i];
        s[64 + i]  = W1[2*i + 1];
        s[128 + i] = b1[i];
        s[192 + i] = b2[i];
        s[256 + i] = W3[i];         // W3[0,:]
        s[320 + i] = W3[64 + i];    // W3[1,:]
    }

    const int wid    = blockIdx.x * (blockDim.x >> 6) + (threadIdx.x >> 6);
    const int nwaves = gridDim.x * (blockDim.x >> 6);

    // ---- Loop-invariant A-operand fragments: W2 and G (trace-folded W2) ----
    // G[k,j] = W2[k,j] * (W3[0,k]*W1[j,0] + W3[1,k]*W1[j,1])
    bf16x8 aW2[4][2], aG[4][2];
#pragma unroll
    for (int mt = 0; mt < 4; ++mt) {
        const int k = mt * 16 + col;
        const float ck = W3[k], dk = W3[64 + k];
#pragma unroll
        for (int jt = 0; jt < 2; ++jt) {
            const float* p = W2 + k * 64 + jt * 32 + quad * 8;
#pragma unroll
            for (int jj = 0; jj < 8; ++jj) {
                int j = jt * 32 + quad * 8 + jj;
                float w2 = p[jj];
                aW2[mt][jt][jj] = f2bf(w2);
                aG[mt][jt][jj]  = f2bf(w2 * fmaf(ck, W1[2*j], dk * W1[2*j+1]));
            }
        }
    }

    const float b30 = b3[0], b31 = b3[1];
    const f32x4 zero4 = {0.f, 0.f, 0.f, 0.f};

    __syncthreads();

    // ---- coalesced z: lanes 0-47 cover the tile's 16 rows x 3 floats ----
    const int lload = lane < 48 ? lane : 47;
    int t = wid;
    float zv = 0.f;
    if (t < ntiles) zv = zin[t * 48 + lload];

    int cofs = 0;   // opaque zero: defeats LICM on the sC re-reads
    for (; t < ntiles; t += nwaves) {
        asm volatile("" : "+v"(cofs));

        // prefetch next tile's z (hides HBM latency under this tile's compute)
        int tn = t + nwaves;
        int tc = tn < ntiles ? tn : t;
        float zvn = zin[tc * 48 + lload];

        float z0 = __shfl(zv, 3 * col);
        float z1 = __shfl(zv, 3 * col + 1);

        // ---- layer 1 (branch-free elu) -> B-fragments for [h | ex1] ----
        bf16x8 Bh[2], Bex[2];
#pragma unroll
        for (int jt = 0; jt < 2; ++jt) {
            int j4 = cofs + jt * 8 + quad * 2;      // f32x4 idx of j0 = jt*32+quad*8
            f32x4 w0a = sC[j4],      w0b = sC[j4 + 1];
            f32x4 w1a = sC[j4 + 16], w1b = sC[j4 + 17];
            f32x4 bba = sC[j4 + 32], bbb = sC[j4 + 33];
            float h[8], ex[8];
#pragma unroll
            for (int jj = 0; jj < 8; ++jj) {
                float w0 = (jj < 4) ? w0a[jj & 3] : w0b[jj & 3];
                float w1 = (jj < 4) ? w1a[jj & 3] : w1b[jj & 3];
                float bb = (jj < 4) ? bba[jj & 3] : bbb[jj & 3];
                float a  = fmaf(w0, z0, fmaf(w1, z1, bb));
                float e  = __expf(fminf(a, 0.f));       // elu'(a)
                ex[jj] = e;
                h[jj]  = fmaxf(a, 0.f) + (e - 1.f);     // elu(a)
            }
            i32x4 ph, pe;
#pragma unroll
            for (int d = 0; d < 4; ++d) {
                ph[d] = cvt_pk_bf16(h[2*d],  h[2*d+1]);
                pe[d] = cvt_pk_bf16(ex[2*d], ex[2*d+1]);
            }
            Bh[jt]  = __builtin_bit_cast(bf16x8, ph);
            Bex[jt] = __builtin_bit_cast(bf16x8, pe);
        }

        // ---- MFMA: accH = W2 * h^T, accT = G * ex1^T  (K=64 as 2 k-steps) ----
        f32x4 accH[4], accT[4];
#pragma unroll
        for (int mt = 0; mt < 4; ++mt) {
            accH[mt] = __builtin_amdgcn_mfma_f32_16x16x32_bf16(aW2[mt][0], Bh[0], zero4, 0, 0, 0);
            accH[mt] = __builtin_amdgcn_mfma_f32_16x16x32_bf16(aW2[mt][1], Bh[1], accH[mt], 0, 0, 0);
            accT[mt] = __builtin_amdgcn_mfma_f32_16x16x32_bf16(aG[mt][0], Bex[0], zero4, 0, 0, 0);
            accT[mt] = __builtin_amdgcn_mfma_f32_16x16x32_bf16(aG[mt][1], Bex[1], accT[mt], 0, 0, 0);
        }

        // ---- epilogue: elu + W3 fold; trace is just ex2 . accT ----
        float o0 = 0.f, o1 = 0.f, trc = 0.f;
#pragma unroll
        for (int mt = 0; mt < 4; ++mt) {
            int k4 = cofs + 48 + mt * 4 + quad;     // f32x4 idx of k0 = mt*16+quad*4
            f32x4 b2v = sC[k4];
            f32x4 w30 = sC[k4 + 16];
            f32x4 w31 = sC[k4 + 32];
#pragma unroll
            for (int i = 0; i < 4; ++i) {
                float a2  = accH[mt][i] + b2v[i];
                float e2  = __expf(fminf(a2, 0.f));     // elu'(a2)
                float hh  = fmaxf(a2, 0.f) + (e2 - 1.f);
                o0  = fmaf(w30[i], hh, o0);
                o1  = fmaf(w31[i], hh, o1);
                trc = fmaf(e2, accT[mt][i], trc);
            }
        }

        // ---- cross-quad reduction (k spans quads): 2 butterfly stages ----
        o0  += __shfl_xor(o0, 16);  o0  += __shfl_xor(o0, 32);
        o1  += __shfl_xor(o1, 16);  o1  += __shfl_xor(o1, 32);
        trc += __shfl_xor(trc, 16); trc += __shfl_xor(trc, 32);

        int row = t * 16 + col;
        if (lane < 16 && row < B) {
            out[3 * row + 0] = o0 + b30;
            out[3 * row + 1] = o1 + b31;
            out[3 * row + 2] = -trc;
        }

        zv = zvn;
    }
}

extern "C" void kernel_launch(void* const* d_in, const int* in_sizes, int n_in,
                              void* d_out, int out_size, void* d_ws, size_t ws_size,
                              hipStream_t stream) {
    // d_in: 0=t(unused) 1=z_and_logp 2=W1 3=b1 4=W2 5=b2 6=W3 7=b3
    const float* zin = (const float*)d_in[1];
    const float* W1  = (const float*)d_in[2];
    const float* b1  = (const float*)d_in[3];
    const float* W2  = (const float*)d_in[4];
    const float* b2  = (const float*)d_in[5];
    const float* W3  = (const float*)d_in[6];
    const float* b3  = (const float*)d_in[7];
    float* out = (float*)d_out;

    int B = in_sizes[1] / 3;
    int ntiles = (B + 15) / 16;
    int grid = 1536;
    odefunc_mfma<<<grid, 256, 0, stream>>>(zin, W1, b1, W2, b2, W3, b3,
                                           out, B, ntiles);
}